// Round 1
// baseline (1888.979 us; speedup 1.0000x reference)
//
#include <hip/hip_runtime.h>
#include <hip/hip_bf16.h>

// GroupedMLP: E=8, T=1024, H=2048, I=5632
// out = (silu(x@w1[:, :I]) * (x@w1[:, I:])) @ w2, per expert.
// Strategy: bf16 MFMA (16x16x32), fp32->bf16 conversion during LDS staging.
// K1: fc1+GLU fused -> inter (bf16) in d_ws. K2: inter @ w2 -> out (fp32).

#define EXPERTS 8
#define TOK     1024
#define HID     2048
#define INTER   5632
#define I2      (2 * INTER)

#define BM  128
#define BK  64
#define LDK 72   // BK + 8 ushorts -> 144B row stride (16B-aligned, breaks bank conflicts)

typedef __bf16 bf16x8 __attribute__((ext_vector_type(8)));
typedef float  f32x4  __attribute__((ext_vector_type(4)));

__device__ __forceinline__ unsigned short f2bf(float f) {
    union { float f; unsigned u; } v; v.f = f;
    unsigned r = v.u + 0x7FFFu + ((v.u >> 16) & 1u);   // RNE
    return (unsigned short)(r >> 16);
}

// ---------------- Kernel 1: fc1 + SiLU-GLU -> inter (bf16) ----------------
// grid = E * (TOK/BM) * (INTER/64), block = 256 (4 waves, each 32 rows x 128 cols)
__global__ __launch_bounds__(256) void k_fc1_glu(
    const float* __restrict__ X, const float* __restrict__ W1,
    unsigned short* __restrict__ inter)
{
    __shared__ unsigned short As[BM][LDK];
    __shared__ unsigned short Bs[128][LDK];

    const int bid = blockIdx.x;
    const int nt  = bid % (INTER / 64);
    const int mt  = (bid / (INTER / 64)) % (TOK / BM);
    const int e   = bid / ((INTER / 64) * (TOK / BM));

    const int t    = threadIdx.x;
    const int lane = t & 63;
    const int w    = t >> 6;

    const int m0      = mt * BM;
    const int rowbase = e * TOK + m0;

    f32x4 acc[2][8];
#pragma unroll
    for (int i = 0; i < 2; ++i)
#pragma unroll
        for (int jj = 0; jj < 8; ++jj) acc[i][jj] = f32x4{0.f, 0.f, 0.f, 0.f};

    // B staging: thread owns one fc1 column j (0..63 -> 'a' cols, 64..127 -> 'b' cols)
    const int jcol = t & 127;
    const int hf   = t >> 7;
    const int gcol = (jcol < 64) ? (nt * 64 + jcol) : (INTER + nt * 64 + (jcol - 64));
    const float* w1e = W1 + (size_t)e * HID * I2;

    for (int k0 = 0; k0 < HID; k0 += BK) {
        // ---- stage A: X[128][64] fp32 -> bf16 (reads 4 consecutive k per lane) ----
#pragma unroll
        for (int it = 0; it < 8; ++it) {
            int lin = it * 256 + t;
            int r   = lin >> 4;
            int kq  = (lin & 15) << 2;
            const float4 v = *reinterpret_cast<const float4*>(
                X + (size_t)(rowbase + r) * HID + k0 + kq);
            ushort4 o;
            o.x = f2bf(v.x); o.y = f2bf(v.y); o.z = f2bf(v.z); o.w = f2bf(v.w);
            *reinterpret_cast<ushort4*>(&As[r][kq]) = o;
        }
        // ---- stage B: W1[k][n] -> Bs[n][k] (k-strided loads, coalesced across lanes) ----
#pragma unroll
        for (int it = 0; it < 8; ++it) {
            int kq = hf * 4 + it * 8;
            const float* p = w1e + (size_t)(k0 + kq) * I2 + gcol;
            float v0 = p[0];
            float v1 = p[I2];
            float v2 = p[2 * I2];
            float v3 = p[3 * I2];
            ushort4 o;
            o.x = f2bf(v0); o.y = f2bf(v1); o.z = f2bf(v2); o.w = f2bf(v3);
            *reinterpret_cast<ushort4*>(&Bs[jcol][kq]) = o;
        }
        __syncthreads();

        // ---- compute: each wave 32 rows x 128 cols, 2x8 fragments ----
#pragma unroll
        for (int kk = 0; kk < 2; ++kk) {
            const int kb = kk * 32 + ((lane >> 4) << 3);
            bf16x8 a0 = *reinterpret_cast<const bf16x8*>(&As[w * 32 + (lane & 15)][kb]);
            bf16x8 a1 = *reinterpret_cast<const bf16x8*>(&As[w * 32 + 16 + (lane & 15)][kb]);
#pragma unroll
            for (int nf = 0; nf < 8; ++nf) {
                bf16x8 b = *reinterpret_cast<const bf16x8*>(&Bs[nf * 16 + (lane & 15)][kb]);
                acc[0][nf] = __builtin_amdgcn_mfma_f32_16x16x32_bf16(a0, b, acc[0][nf], 0, 0, 0);
                acc[1][nf] = __builtin_amdgcn_mfma_f32_16x16x32_bf16(a1, b, acc[1][nf], 0, 0, 0);
            }
        }
        __syncthreads();
    }

    // ---- epilogue: inter = silu(a) * b, bf16 store ----
    // C layout: col = lane&15, row = (lane>>4)*4 + reg (verified gfx950 mapping)
    const int rl0 = w * 32 + ((lane >> 4) << 2);
    const int cl  = lane & 15;
#pragma unroll
    for (int mf = 0; mf < 2; ++mf) {
#pragma unroll
        for (int nfa = 0; nfa < 4; ++nfa) {
            f32x4 va = acc[mf][nfa];
            f32x4 vb = acc[mf][nfa + 4];
#pragma unroll
            for (int r = 0; r < 4; ++r) {
                float a = va[r], b = vb[r];
                float s = a / (1.f + __expf(-a)) * b;     // silu(a) * b
                int row = rowbase + rl0 + mf * 16 + r;
                int col = nt * 64 + nfa * 16 + cl;
                inter[(size_t)row * INTER + col] = f2bf(s);
            }
        }
    }
}

// ---------------- Kernel 2: inter (bf16) @ w2 -> out (fp32) ----------------
// grid = E * (TOK/BM) * (HID/128), block = 256
__global__ __launch_bounds__(256) void k_fc2(
    const unsigned short* __restrict__ inter, const float* __restrict__ W2,
    float* __restrict__ out)
{
    __shared__ unsigned short As[BM][LDK];
    __shared__ unsigned short Bs[128][LDK];

    const int bid = blockIdx.x;
    const int nt  = bid % (HID / 128);
    const int mt  = (bid / (HID / 128)) % (TOK / BM);
    const int e   = bid / ((HID / 128) * (TOK / BM));

    const int t    = threadIdx.x;
    const int lane = t & 63;
    const int w    = t >> 6;

    const int m0      = mt * BM;
    const int rowbase = e * TOK + m0;

    f32x4 acc[2][8];
#pragma unroll
    for (int i = 0; i < 2; ++i)
#pragma unroll
        for (int jj = 0; jj < 8; ++jj) acc[i][jj] = f32x4{0.f, 0.f, 0.f, 0.f};

    const int jcol = t & 127;
    const int hf   = t >> 7;
    const int gcol = nt * 128 + jcol;
    const float* w2e = W2 + (size_t)e * INTER * HID;

    for (int k0 = 0; k0 < INTER; k0 += BK) {
        // ---- stage A: inter bf16 passthrough (16B vector copies) ----
#pragma unroll
        for (int it = 0; it < 4; ++it) {
            int lin = it * 256 + t;
            int r   = lin >> 3;
            int kq  = (lin & 7) << 3;
            uint4 v = *reinterpret_cast<const uint4*>(
                inter + (size_t)(rowbase + r) * INTER + k0 + kq);
            *reinterpret_cast<uint4*>(&As[r][kq]) = v;
        }
        // ---- stage B: W2[k][n] -> Bs[n][k] with fp32->bf16 ----
#pragma unroll
        for (int it = 0; it < 8; ++it) {
            int kq = hf * 4 + it * 8;
            const float* p = w2e + (size_t)(k0 + kq) * HID + gcol;
            float v0 = p[0];
            float v1 = p[HID];
            float v2 = p[2 * HID];
            float v3 = p[3 * HID];
            ushort4 o;
            o.x = f2bf(v0); o.y = f2bf(v1); o.z = f2bf(v2); o.w = f2bf(v3);
            *reinterpret_cast<ushort4*>(&Bs[jcol][kq]) = o;
        }
        __syncthreads();

#pragma unroll
        for (int kk = 0; kk < 2; ++kk) {
            const int kb = kk * 32 + ((lane >> 4) << 3);
            bf16x8 a0 = *reinterpret_cast<const bf16x8*>(&As[w * 32 + (lane & 15)][kb]);
            bf16x8 a1 = *reinterpret_cast<const bf16x8*>(&As[w * 32 + 16 + (lane & 15)][kb]);
#pragma unroll
            for (int nf = 0; nf < 8; ++nf) {
                bf16x8 b = *reinterpret_cast<const bf16x8*>(&Bs[nf * 16 + (lane & 15)][kb]);
                acc[0][nf] = __builtin_amdgcn_mfma_f32_16x16x32_bf16(a0, b, acc[0][nf], 0, 0, 0);
                acc[1][nf] = __builtin_amdgcn_mfma_f32_16x16x32_bf16(a1, b, acc[1][nf], 0, 0, 0);
            }
        }
        __syncthreads();
    }

    // ---- epilogue: fp32 store ----
    const int rl0 = w * 32 + ((lane >> 4) << 2);
    const int cl  = lane & 15;
#pragma unroll
    for (int mf = 0; mf < 2; ++mf) {
#pragma unroll
        for (int nf = 0; nf < 8; ++nf) {
            f32x4 v = acc[mf][nf];
#pragma unroll
            for (int r = 0; r < 4; ++r) {
                int row = rowbase + rl0 + mf * 16 + r;
                int col = nt * 128 + nf * 16 + cl;
                out[(size_t)row * HID + col] = v[r];
            }
        }
    }
}

extern "C" void kernel_launch(void* const* d_in, const int* in_sizes, int n_in,
                              void* d_out, int out_size, void* d_ws, size_t ws_size,
                              hipStream_t stream) {
    const float* X  = (const float*)d_in[0];
    const float* W1 = (const float*)d_in[1];
    const float* W2 = (const float*)d_in[2];
    // d_in[3] = tokens_per_expert, statically T=1024 each -> ignored.
    float* out = (float*)d_out;
    unsigned short* inter = (unsigned short*)d_ws;  // [E*T][INTER] bf16, 92.3 MB

    dim3 blk(256);
    k_fc1_glu<<<EXPERTS * (TOK / BM) * (INTER / 64), blk, 0, stream>>>(X, W1, inter);
    k_fc2  <<<EXPERTS * (TOK / BM) * (HID / 128),   blk, 0, stream>>>(inter, W2, out);
}

// Round 2
// 1246.453 us; speedup vs baseline: 1.5155x; 1.5155x over previous
//
#include <hip/hip_runtime.h>
#include <hip/hip_bf16.h>

// GroupedMLP: E=8, T=1024, H=2048, I=5632
// Fast path (needs ~648 MiB ws): convert X/w1/w2 to bf16 GEMM-native layouts,
// then two m97-structure MFMA GEMMs (global_load_lds width-16 staging).
// w1t is transposed AND GLU-pair interleaved: w1t[2n+c][h] = w1[h][c*I+n],
// so fc1's epilogue fuses silu(a)*b via one __shfl_xor(1).
// Fallback path (ws < need): round-1 kernels (only need 92 MB inter).

#define EXPERTS 8
#define TOK     1024
#define HID     2048
#define INTER   5632
#define I2      (2 * INTER)

typedef __bf16 bf16x8 __attribute__((ext_vector_type(8)));
typedef float  f32x4  __attribute__((ext_vector_type(4)));

__device__ __forceinline__ unsigned short f2bf(float f) {
    union { float f; unsigned u; } v; v.f = f;
    unsigned r = v.u + 0x7FFFu + ((v.u >> 16) & 1u);   // RNE
    return (unsigned short)(r >> 16);
}

__device__ __forceinline__ void gload_lds16(const void* g, void* l) {
    __builtin_amdgcn_global_load_lds(
        (const __attribute__((address_space(1))) void*)g,
        (__attribute__((address_space(3))) void*)l, 16, 0, 0);
}

// ---------------- converts ----------------

// X fp32 -> bf16, 8 elems/thread
__global__ __launch_bounds__(256) void k_cvt_x(const float* __restrict__ X,
                                               unsigned short* __restrict__ Xb) {
    size_t i = ((size_t)blockIdx.x * 256 + threadIdx.x) * 8;
    float4 v0 = *reinterpret_cast<const float4*>(X + i);
    float4 v1 = *reinterpret_cast<const float4*>(X + i + 4);
    uint4 o;
    o.x = (unsigned)f2bf(v0.x) | ((unsigned)f2bf(v0.y) << 16);
    o.y = (unsigned)f2bf(v0.z) | ((unsigned)f2bf(v0.w) << 16);
    o.z = (unsigned)f2bf(v1.x) | ((unsigned)f2bf(v1.y) << 16);
    o.w = (unsigned)f2bf(v1.z) | ((unsigned)f2bf(v1.w) << 16);
    *reinterpret_cast<uint4*>(Xb + i) = o;
}

// w1[e][h][2I] fp32 -> w1t[e][pc][h] bf16, pc = 2n + c where col = c*I + n
__global__ __launch_bounds__(256) void k_cvt_w1(const float* __restrict__ W1,
                                                unsigned short* __restrict__ W1T) {
    __shared__ unsigned short lds[64][72];
    const int bid = blockIdx.x;
    const int hb = bid % (HID / 64);
    const int pb = (bid / (HID / 64)) % (I2 / 64);
    const int e  = bid / ((HID / 64) * (I2 / 64));
    const int h0 = hb * 64, p0 = pb * 64, n0 = p0 >> 1;
    const float* w1e = W1 + (size_t)e * HID * I2;
    const int t = threadIdx.x;
#pragma unroll
    for (int it = 0; it < 16; ++it) {
        int lin   = it * 256 + t;
        int n_off = lin & 31;
        int c     = (lin >> 5) & 1;
        int h_off = lin >> 6;
        float v = w1e[(size_t)(h0 + h_off) * I2 + c * INTER + n0 + n_off];
        lds[2 * n_off + c][h_off] = f2bf(v);
    }
    __syncthreads();
    unsigned short* o = W1T + (size_t)e * I2 * HID;
#pragma unroll
    for (int it = 0; it < 4; ++it) {
        int lin = it * 256 + t;
        int r   = lin >> 4;
        int co  = (lin & 15) * 4;
        ushort4 v = *reinterpret_cast<ushort4*>(&lds[r][co]);
        *reinterpret_cast<ushort4*>(o + (size_t)(p0 + r) * HID + h0 + co) = v;
    }
}

// w2[e][i][H] fp32 -> w2t[e][h][i] bf16 (plain transpose)
__global__ __launch_bounds__(256) void k_cvt_w2(const float* __restrict__ W2,
                                                unsigned short* __restrict__ W2T) {
    __shared__ unsigned short lds[64][72];
    const int bid = blockIdx.x;
    const int ib = bid % (INTER / 64);
    const int hb = (bid / (INTER / 64)) % (HID / 64);
    const int e  = bid / ((INTER / 64) * (HID / 64));
    const int i0 = ib * 64, h0 = hb * 64;
    const float* w2e = W2 + (size_t)e * INTER * HID;
    const int t = threadIdx.x;
#pragma unroll
    for (int it = 0; it < 16; ++it) {
        int lin   = it * 256 + t;
        int h_off = lin & 63;
        int i_off = lin >> 6;
        float v = w2e[(size_t)(i0 + i_off) * HID + h0 + h_off];
        lds[h_off][i_off] = f2bf(v);
    }
    __syncthreads();
    unsigned short* o = W2T + (size_t)e * HID * INTER;
#pragma unroll
    for (int it = 0; it < 4; ++it) {
        int lin = it * 256 + t;
        int r   = lin >> 4;
        int co  = (lin & 15) * 4;
        ushort4 v = *reinterpret_cast<ushort4*>(&lds[r][co]);
        *reinterpret_cast<ushort4*>(o + (size_t)(h0 + r) * INTER + i0 + co) = v;
    }
}

// ---------------- m97-structure GEMMs ----------------
// 128x128 tile, 4 waves (2x2), each wave 64x64 = 4x4 fragments of 16x16x32.
// Linear LDS [128][64] bf16, staged via global_load_lds width 16.

// fc1: Xb[8192][2048] @ w1t^T -> inter bf16 with fused GLU
__global__ __launch_bounds__(256) void k_fc1(const unsigned short* __restrict__ A,
                                             const unsigned short* __restrict__ BT,
                                             unsigned short* __restrict__ Cinter) {
    __shared__ unsigned short As[128 * 64];
    __shared__ unsigned short Bs[128 * 64];
    const int NT = I2 / 128;  // 88
    const int bid = blockIdx.x;
    const int nt = bid % NT;
    const int mt = (bid / NT) % (TOK / 128);
    const int e  = bid / (NT * (TOK / 128));
    const int t = threadIdx.x, lane = t & 63, w = t >> 6;
    const int m0 = e * TOK + mt * 128;
    const int n0 = nt * 128;
    const unsigned short* Ab = A + (size_t)m0 * HID;
    const unsigned short* Bb = BT + (size_t)e * I2 * HID + (size_t)n0 * HID;

    f32x4 acc[4][4];
#pragma unroll
    for (int i = 0; i < 4; ++i)
#pragma unroll
        for (int j = 0; j < 4; ++j) acc[i][j] = f32x4{0.f, 0.f, 0.f, 0.f};

    const int srow = lane >> 3;        // 0..7
    const int scol = (lane & 7) * 8;   // element offset (16B per lane)

    for (int k0 = 0; k0 < HID; k0 += 64) {
#pragma unroll
        for (int i = 0; i < 4; ++i) {
            int j   = w * 4 + i;       // staging instr 0..15
            int row = j * 8 + srow;
            gload_lds16(Ab + (size_t)row * HID + k0 + scol, (void*)(As + j * 512));
            gload_lds16(Bb + (size_t)row * HID + k0 + scol, (void*)(Bs + j * 512));
        }
        __syncthreads();
        const int wr = (w >> 1) * 64, wc = (w & 1) * 64;
#pragma unroll
        for (int kk = 0; kk < 2; ++kk) {
            const int kb = kk * 32 + ((lane >> 4) << 3);
            bf16x8 a[4], b[4];
#pragma unroll
            for (int mf = 0; mf < 4; ++mf)
                a[mf] = *reinterpret_cast<const bf16x8*>(As + (wr + mf * 16 + (lane & 15)) * 64 + kb);
#pragma unroll
            for (int nf = 0; nf < 4; ++nf)
                b[nf] = *reinterpret_cast<const bf16x8*>(Bs + (wc + nf * 16 + (lane & 15)) * 64 + kb);
#pragma unroll
            for (int mf = 0; mf < 4; ++mf)
#pragma unroll
                for (int nf = 0; nf < 4; ++nf)
                    acc[mf][nf] = __builtin_amdgcn_mfma_f32_16x16x32_bf16(a[mf], b[nf], acc[mf][nf], 0, 0, 0);
        }
        __syncthreads();
    }

    // epilogue: even permuted col = a, odd = b (adjacent lanes) -> silu(a)*b
    const int wr = (w >> 1) * 64, wc = (w & 1) * 64;
    const int cl = lane & 15;
#pragma unroll
    for (int mf = 0; mf < 4; ++mf)
#pragma unroll
        for (int nf = 0; nf < 4; ++nf)
#pragma unroll
            for (int r = 0; r < 4; ++r) {
                float v  = acc[mf][nf][r];
                float pv = __shfl_xor(v, 1);
                if ((lane & 1) == 0) {
                    float s = v / (1.f + __expf(-v)) * pv;
                    int row = m0 + wr + mf * 16 + ((lane >> 4) << 2) + r;
                    int pc  = n0 + wc + nf * 16 + cl;
                    Cinter[(size_t)row * INTER + (pc >> 1)] = f2bf(s);
                }
            }
}

// fc2: inter[8192][5632] @ w2t^T -> out fp32
__global__ __launch_bounds__(256) void k_fc2n(const unsigned short* __restrict__ A,
                                              const unsigned short* __restrict__ BT,
                                              float* __restrict__ out) {
    __shared__ unsigned short As[128 * 64];
    __shared__ unsigned short Bs[128 * 64];
    const int NT = HID / 128;  // 16
    const int bid = blockIdx.x;
    const int nt = bid % NT;
    const int mt = (bid / NT) % (TOK / 128);
    const int e  = bid / (NT * (TOK / 128));
    const int t = threadIdx.x, lane = t & 63, w = t >> 6;
    const int m0 = e * TOK + mt * 128;
    const int n0 = nt * 128;
    const unsigned short* Ab = A + (size_t)m0 * INTER;
    const unsigned short* Bb = BT + (size_t)e * HID * INTER + (size_t)n0 * INTER;

    f32x4 acc[4][4];
#pragma unroll
    for (int i = 0; i < 4; ++i)
#pragma unroll
        for (int j = 0; j < 4; ++j) acc[i][j] = f32x4{0.f, 0.f, 0.f, 0.f};

    const int srow = lane >> 3;
    const int scol = (lane & 7) * 8;

    for (int k0 = 0; k0 < INTER; k0 += 64) {
#pragma unroll
        for (int i = 0; i < 4; ++i) {
            int j   = w * 4 + i;
            int row = j * 8 + srow;
            gload_lds16(Ab + (size_t)row * INTER + k0 + scol, (void*)(As + j * 512));
            gload_lds16(Bb + (size_t)row * INTER + k0 + scol, (void*)(Bs + j * 512));
        }
        __syncthreads();
        const int wr = (w >> 1) * 64, wc = (w & 1) * 64;
#pragma unroll
        for (int kk = 0; kk < 2; ++kk) {
            const int kb = kk * 32 + ((lane >> 4) << 3);
            bf16x8 a[4], b[4];
#pragma unroll
            for (int mf = 0; mf < 4; ++mf)
                a[mf] = *reinterpret_cast<const bf16x8*>(As + (wr + mf * 16 + (lane & 15)) * 64 + kb);
#pragma unroll
            for (int nf = 0; nf < 4; ++nf)
                b[nf] = *reinterpret_cast<const bf16x8*>(Bs + (wc + nf * 16 + (lane & 15)) * 64 + kb);
#pragma unroll
            for (int mf = 0; mf < 4; ++mf)
#pragma unroll
                for (int nf = 0; nf < 4; ++nf)
                    acc[mf][nf] = __builtin_amdgcn_mfma_f32_16x16x32_bf16(a[mf], b[nf], acc[mf][nf], 0, 0, 0);
        }
        __syncthreads();
    }

    const int wr = (w >> 1) * 64, wc = (w & 1) * 64;
    const int cl = lane & 15;
#pragma unroll
    for (int mf = 0; mf < 4; ++mf)
#pragma unroll
        for (int nf = 0; nf < 4; ++nf)
#pragma unroll
            for (int r = 0; r < 4; ++r) {
                int row = m0 + wr + mf * 16 + ((lane >> 4) << 2) + r;
                int col = n0 + wc + nf * 16 + cl;
                out[(size_t)row * HID + col] = acc[mf][nf][r];
            }
}

// ---------------- fallback (round-1 kernels, need only 92 MB ws) ----------------

#define BM  128
#define BK  64
#define LDK 72

__global__ __launch_bounds__(256) void k_fc1_glu_fb(
    const float* __restrict__ X, const float* __restrict__ W1,
    unsigned short* __restrict__ inter)
{
    __shared__ unsigned short As[BM][LDK];
    __shared__ unsigned short Bs[128][LDK];
    const int bid = blockIdx.x;
    const int nt  = bid % (INTER / 64);
    const int mt  = (bid / (INTER / 64)) % (TOK / BM);
    const int e   = bid / ((INTER / 64) * (TOK / BM));
    const int t = threadIdx.x, lane = t & 63, w = t >> 6;
    const int m0 = mt * BM;
    const int rowbase = e * TOK + m0;
    f32x4 acc[2][8];
#pragma unroll
    for (int i = 0; i < 2; ++i)
#pragma unroll
        for (int jj = 0; jj < 8; ++jj) acc[i][jj] = f32x4{0.f, 0.f, 0.f, 0.f};
    const int jcol = t & 127;
    const int hf   = t >> 7;
    const int gcol = (jcol < 64) ? (nt * 64 + jcol) : (INTER + nt * 64 + (jcol - 64));
    const float* w1e = W1 + (size_t)e * HID * I2;
    for (int k0 = 0; k0 < HID; k0 += BK) {
#pragma unroll
        for (int it = 0; it < 8; ++it) {
            int lin = it * 256 + t;
            int r   = lin >> 4;
            int kq  = (lin & 15) << 2;
            const float4 v = *reinterpret_cast<const float4*>(
                X + (size_t)(rowbase + r) * HID + k0 + kq);
            ushort4 o;
            o.x = f2bf(v.x); o.y = f2bf(v.y); o.z = f2bf(v.z); o.w = f2bf(v.w);
            *reinterpret_cast<ushort4*>(&As[r][kq]) = o;
        }
#pragma unroll
        for (int it = 0; it < 8; ++it) {
            int kq = hf * 4 + it * 8;
            const float* p = w1e + (size_t)(k0 + kq) * I2 + gcol;
            float v0 = p[0], v1 = p[I2], v2 = p[2 * I2], v3 = p[3 * I2];
            ushort4 o;
            o.x = f2bf(v0); o.y = f2bf(v1); o.z = f2bf(v2); o.w = f2bf(v3);
            *reinterpret_cast<ushort4*>(&Bs[jcol][kq]) = o;
        }
        __syncthreads();
#pragma unroll
        for (int kk = 0; kk < 2; ++kk) {
            const int kb = kk * 32 + ((lane >> 4) << 3);
            bf16x8 a0 = *reinterpret_cast<const bf16x8*>(&As[w * 32 + (lane & 15)][kb]);
            bf16x8 a1 = *reinterpret_cast<const bf16x8*>(&As[w * 32 + 16 + (lane & 15)][kb]);
#pragma unroll
            for (int nf = 0; nf < 8; ++nf) {
                bf16x8 b = *reinterpret_cast<const bf16x8*>(&Bs[nf * 16 + (lane & 15)][kb]);
                acc[0][nf] = __builtin_amdgcn_mfma_f32_16x16x32_bf16(a0, b, acc[0][nf], 0, 0, 0);
                acc[1][nf] = __builtin_amdgcn_mfma_f32_16x16x32_bf16(a1, b, acc[1][nf], 0, 0, 0);
            }
        }
        __syncthreads();
    }
    const int rl0 = w * 32 + ((lane >> 4) << 2);
    const int cl  = lane & 15;
#pragma unroll
    for (int mf = 0; mf < 2; ++mf)
#pragma unroll
        for (int nfa = 0; nfa < 4; ++nfa) {
            f32x4 va = acc[mf][nfa];
            f32x4 vb = acc[mf][nfa + 4];
#pragma unroll
            for (int r = 0; r < 4; ++r) {
                float a = va[r], b = vb[r];
                float s = a / (1.f + __expf(-a)) * b;
                int row = rowbase + rl0 + mf * 16 + r;
                int col = nt * 64 + nfa * 16 + cl;
                inter[(size_t)row * INTER + col] = f2bf(s);
            }
        }
}

__global__ __launch_bounds__(256) void k_fc2_fb(
    const unsigned short* __restrict__ inter, const float* __restrict__ W2,
    float* __restrict__ out)
{
    __shared__ unsigned short As[BM][LDK];
    __shared__ unsigned short Bs[128][LDK];
    const int bid = blockIdx.x;
    const int nt  = bid % (HID / 128);
    const int mt  = (bid / (HID / 128)) % (TOK / BM);
    const int e   = bid / ((HID / 128) * (TOK / BM));
    const int t = threadIdx.x, lane = t & 63, w = t >> 6;
    const int m0 = mt * BM;
    const int rowbase = e * TOK + m0;
    f32x4 acc[2][8];
#pragma unroll
    for (int i = 0; i < 2; ++i)
#pragma unroll
        for (int jj = 0; jj < 8; ++jj) acc[i][jj] = f32x4{0.f, 0.f, 0.f, 0.f};
    const int jcol = t & 127;
    const int hf   = t >> 7;
    const int gcol = nt * 128 + jcol;
    const float* w2e = W2 + (size_t)e * INTER * HID;
    for (int k0 = 0; k0 < INTER; k0 += BK) {
#pragma unroll
        for (int it = 0; it < 4; ++it) {
            int lin = it * 256 + t;
            int r   = lin >> 3;
            int kq  = (lin & 7) << 3;
            uint4 v = *reinterpret_cast<const uint4*>(
                inter + (size_t)(rowbase + r) * INTER + k0 + kq);
            *reinterpret_cast<uint4*>(&As[r][kq]) = v;
        }
#pragma unroll
        for (int it = 0; it < 8; ++it) {
            int kq = hf * 4 + it * 8;
            const float* p = w2e + (size_t)(k0 + kq) * HID + gcol;
            float v0 = p[0], v1 = p[HID], v2 = p[2 * HID], v3 = p[3 * HID];
            ushort4 o;
            o.x = f2bf(v0); o.y = f2bf(v1); o.z = f2bf(v2); o.w = f2bf(v3);
            *reinterpret_cast<ushort4*>(&Bs[jcol][kq]) = o;
        }
        __syncthreads();
#pragma unroll
        for (int kk = 0; kk < 2; ++kk) {
            const int kb = kk * 32 + ((lane >> 4) << 3);
            bf16x8 a0 = *reinterpret_cast<const bf16x8*>(&As[w * 32 + (lane & 15)][kb]);
            bf16x8 a1 = *reinterpret_cast<const bf16x8*>(&As[w * 32 + 16 + (lane & 15)][kb]);
#pragma unroll
            for (int nf = 0; nf < 8; ++nf) {
                bf16x8 b = *reinterpret_cast<const bf16x8*>(&Bs[nf * 16 + (lane & 15)][kb]);
                acc[0][nf] = __builtin_amdgcn_mfma_f32_16x16x32_bf16(a0, b, acc[0][nf], 0, 0, 0);
                acc[1][nf] = __builtin_amdgcn_mfma_f32_16x16x32_bf16(a1, b, acc[1][nf], 0, 0, 0);
            }
        }
        __syncthreads();
    }
    const int rl0 = w * 32 + ((lane >> 4) << 2);
    const int cl  = lane & 15;
#pragma unroll
    for (int mf = 0; mf < 2; ++mf)
#pragma unroll
        for (int nf = 0; nf < 8; ++nf) {
            f32x4 v = acc[mf][nf];
#pragma unroll
            for (int r = 0; r < 4; ++r) {
                int row = rowbase + rl0 + mf * 16 + r;
                int col = nt * 128 + nf * 16 + cl;
                out[(size_t)row * HID + col] = v[r];
            }
        }
}

// ---------------- launch ----------------

extern "C" void kernel_launch(void* const* d_in, const int* in_sizes, int n_in,
                              void* d_out, int out_size, void* d_ws, size_t ws_size,
                              hipStream_t stream) {
    const float* X  = (const float*)d_in[0];
    const float* W1 = (const float*)d_in[1];
    const float* W2 = (const float*)d_in[2];
    float* out = (float*)d_out;

    const size_t XB_B   = (size_t)EXPERTS * TOK * HID * 2;        //  33.5 MB
    const size_t W1T_B  = (size_t)EXPERTS * I2 * HID * 2;         // 369.1 MB
    const size_t W2T_B  = (size_t)EXPERTS * HID * INTER * 2;      // 184.5 MB
    const size_t INT_B  = (size_t)EXPERTS * TOK * INTER * 2;      //  92.3 MB
    const size_t need   = XB_B + W1T_B + W2T_B + INT_B;

    dim3 blk(256);
    if (ws_size >= need) {
        unsigned short* Xb    = (unsigned short*)d_ws;
        unsigned short* w1t   = (unsigned short*)((char*)d_ws + XB_B);
        unsigned short* w2t   = (unsigned short*)((char*)d_ws + XB_B + W1T_B);
        unsigned short* inter = (unsigned short*)((char*)d_ws + XB_B + W1T_B + W2T_B);

        k_cvt_x <<<(EXPERTS * TOK * HID) / (256 * 8), blk, 0, stream>>>(X, Xb);
        k_cvt_w1<<<EXPERTS * (I2 / 64) * (HID / 64),  blk, 0, stream>>>(W1, w1t);
        k_cvt_w2<<<EXPERTS * (HID / 64) * (INTER / 64), blk, 0, stream>>>(W2, w2t);
        k_fc1   <<<EXPERTS * (TOK / 128) * (I2 / 128),  blk, 0, stream>>>(Xb, w1t, inter);
        k_fc2n  <<<EXPERTS * (TOK / 128) * (HID / 128), blk, 0, stream>>>(inter, w2t, out);
    } else {
        unsigned short* inter = (unsigned short*)d_ws;
        k_fc1_glu_fb<<<EXPERTS * (TOK / BM) * (INTER / 64), blk, 0, stream>>>(X, W1, inter);
        k_fc2_fb    <<<EXPERTS * (TOK / BM) * (HID / 128),  blk, 0, stream>>>(inter, W2, out);
    }
}